// Round 17
// baseline (370.133 us; speedup 1.0000x reference)
//
#include <hip/hip_runtime.h>
#include <stdint.h>

#define EPSF 1e-6f

typedef unsigned short u16;
typedef __attribute__((ext_vector_type(8))) short short8;
typedef __attribute__((ext_vector_type(4))) float f32x4;

__device__ __forceinline__ float us2f(u16 u) {
  union { float f; unsigned int i; } c; c.i = ((unsigned int)u) << 16; return c.f;
}
__device__ __forceinline__ u16 f2bfu(float f) {
  union { float f; unsigned int i; } c; c.f = f;
  unsigned int i = c.i;
  return (u16)((i + 0x7FFFu + ((i >> 16) & 1u)) >> 16);
}
__device__ __forceinline__ float sigm(float x) { return 1.f / (1.f + __expf(-x)); }

typedef __attribute__((address_space(3))) unsigned int lds_u32;
typedef const __attribute__((address_space(1))) unsigned int glb_u32;
__device__ __forceinline__ void gl_lds16(const u16* g, u16* l) {
  __builtin_amdgcn_global_load_lds((glb_u32*)g, (lds_u32*)l, 16, 0, 0);
}

// ---------------- fused prep: x cvt (blocks 0..24575) + W transposes ----------------
__global__ void k_prep(const float* __restrict__ x, u16* __restrict__ xbf,
                       const float* __restrict__ Wqkv, u16* __restrict__ WqT,
                       const float* __restrict__ Wproj, u16* __restrict__ WpT) {
  __shared__ float tile[32][33];
  const int b = blockIdx.x;
  if (b < 24576) {
    const int i = b * 256 + threadIdx.x;
    float4 v = ((const float4*)x)[i];
    ushort4 o;
    o.x = f2bfu(v.x); o.y = f2bfu(v.y); o.z = f2bfu(v.z); o.w = f2bfu(v.w);
    ((ushort4*)xbf)[i] = o;
    return;
  }
  const float* in; u16* out; int R, C, bx, by;
  if (b < 24576 + 1728) {
    const int id = b - 24576; in = Wqkv; out = WqT; R = 768; C = 2304; bx = id % 72; by = id / 72;
  } else {
    const int id = b - 26304; in = Wproj; out = WpT; R = 768; C = 768; bx = id % 24; by = id / 24;
  }
  const int tx = threadIdx.x & 31, ty = threadIdx.x >> 5;
  const int c0 = bx << 5, r0 = by << 5;
  for (int i = ty; i < 32; i += 8) tile[i][tx] = in[(size_t)(r0 + i) * C + c0 + tx];
  __syncthreads();
  for (int i = ty; i < 32; i += 8) out[(size_t)(c0 + i) * R + r0 + tx] = f2bfu(tile[tx][i]);
}

// ---------------- GEMM: 256x192 tile, 8 waves, BK=64, 1 barrier/tile ----------------
// Round-16 structure; staging for tile t+1 now issued in ONE clump right after the first frag
// reads (max latency-cover before end-of-tile vmcnt(0)), single setprio region over 48 MFMA.
// Correctness unchanged: no cross-wave hazard within a tile; tile handoff = vmcnt(0) memory
// clobber + one s_barrier. Bit-identical math.
template <int MODE>
__global__ __launch_bounds__(512, 1) void k_gemm(
    const u16* __restrict__ A, const u16* __restrict__ BT,
    const float* __restrict__ bias,
    u16* __restrict__ qkvo, float* __restrict__ qsum, float* __restrict__ ksum,
    float* __restrict__ outf)
{
  __shared__ __align__(16) u16 smem[57344];  // 112 KB
  const int tid = threadIdx.x;
  const int lane = tid & 63;
  const int wid = tid >> 6;           // 0..7
  const int wm = wid >> 2, wn = wid & 3;
  // bijective XCD swizzle (nwg % 8 == 0 for both grids)
  const int nx = gridDim.x;
  int lid = blockIdx.y * nx + blockIdx.x;
  const int q8 = (nx * gridDim.y) >> 3;
  lid = (lid & 7) * q8 + (lid >> 3);
  const int m0 = (lid / nx) << 8;
  const int n0 = (lid % nx) * 192;

  const int rowL0 = tid >> 3;                      // 0..63
  const int gc = (tid & 7) ^ (rowL0 & 7);
  const u16* gA = A  + (size_t)(m0 + rowL0) * 768 + (gc << 3);
  const u16* gB = BT + (size_t)(n0 + rowL0) * 768 + (gc << 3);

  const int r16 = lane & 15;
  const int sgrp = lane >> 4;
  const int xk = r16 & 7;
  const int coff0 = ((sgrp) ^ xk) << 3;            // kslot 0 chunk offset (elems)
  const int coff1 = ((4 + sgrp) ^ xk) << 3;        // kslot 1
  int offB[3];
#pragma unroll
  for (int nj = 0; nj < 3; ++nj) {
    const int ub = wn * 48 + (nj << 4);            // 16-row band base (never straddles 64)
    offB[nj] = ((ub >> 6) << 12) + (((ub & 63) + r16) << 6);
  }

  f32x4 acc[8][3];
#pragma unroll
  for (int i = 0; i < 8; ++i)
#pragma unroll
    for (int j = 0; j < 3; ++j) acc[i][j] = (f32x4){0.f, 0.f, 0.f, 0.f};

#define STAGEA(tt, y)                                                         \
  do {                                                                        \
    u16* dst = &smem[(((tt) & 1) * 28672) + ((y) << 13) + (tid << 3)];        \
    const u16* s = gA + (size_t)(y) * 98304 + (tt) * 64;                      \
    gl_lds16(s, dst);                                                         \
    gl_lds16(s + 49152, dst + 4096);                                          \
  } while (0)

#define STAGEB(tt, u)                                                         \
  do {                                                                        \
    u16* dst = &smem[(((tt) & 1) * 28672) + 16384 + ((u) << 12) + (tid << 3)];\
    gl_lds16(gB + (size_t)(u) * 49152 + (tt) * 64, dst);                      \
  } while (0)

#define RDA(mi, co) (*(const short8*)(pa + ((((mi) << 4) + r16) << 6) + (co)))
#define RDB(nj, co) (*(const short8*)(pb + offB[nj] + (co)))

#define MFMA12(P, A00, A01, A10, A11)                                                               \
  do {                                                                                              \
    acc[2*(P)  ][0] = __builtin_amdgcn_mfma_f32_16x16x32_bf16(A00, bf[0][0], acc[2*(P)  ][0],0,0,0);\
    acc[2*(P)  ][1] = __builtin_amdgcn_mfma_f32_16x16x32_bf16(A00, bf[1][0], acc[2*(P)  ][1],0,0,0);\
    acc[2*(P)  ][2] = __builtin_amdgcn_mfma_f32_16x16x32_bf16(A00, bf[2][0], acc[2*(P)  ][2],0,0,0);\
    acc[2*(P)+1][0] = __builtin_amdgcn_mfma_f32_16x16x32_bf16(A10, bf[0][0], acc[2*(P)+1][0],0,0,0);\
    acc[2*(P)+1][1] = __builtin_amdgcn_mfma_f32_16x16x32_bf16(A10, bf[1][0], acc[2*(P)+1][1],0,0,0);\
    acc[2*(P)+1][2] = __builtin_amdgcn_mfma_f32_16x16x32_bf16(A10, bf[2][0], acc[2*(P)+1][2],0,0,0);\
    acc[2*(P)  ][0] = __builtin_amdgcn_mfma_f32_16x16x32_bf16(A01, bf[0][1], acc[2*(P)  ][0],0,0,0);\
    acc[2*(P)  ][1] = __builtin_amdgcn_mfma_f32_16x16x32_bf16(A01, bf[1][1], acc[2*(P)  ][1],0,0,0);\
    acc[2*(P)  ][2] = __builtin_amdgcn_mfma_f32_16x16x32_bf16(A01, bf[2][1], acc[2*(P)  ][2],0,0,0);\
    acc[2*(P)+1][0] = __builtin_amdgcn_mfma_f32_16x16x32_bf16(A11, bf[0][1], acc[2*(P)+1][0],0,0,0);\
    acc[2*(P)+1][1] = __builtin_amdgcn_mfma_f32_16x16x32_bf16(A11, bf[1][1], acc[2*(P)+1][1],0,0,0);\
    acc[2*(P)+1][2] = __builtin_amdgcn_mfma_f32_16x16x32_bf16(A11, bf[2][1], acc[2*(P)+1][2],0,0,0);\
  } while (0)

  STAGEA(0, 0); STAGEA(0, 1); STAGEB(0, 0); STAGEB(0, 1); STAGEB(0, 2);
  asm volatile("s_waitcnt vmcnt(0)" ::: "memory");
  __builtin_amdgcn_s_barrier();

  for (int t = 0; t < 12; ++t) {
    const u16* pa = &smem[(t & 1) * 28672 + (wm << 13)];
    const u16* pb = &smem[(t & 1) * 28672 + 16384];
    short8 bf[3][2];
    bf[0][0] = RDB(0, coff0); bf[0][1] = RDB(0, coff1);
    bf[1][0] = RDB(1, coff0); bf[1][1] = RDB(1, coff1);
    bf[2][0] = RDB(2, coff0); bf[2][1] = RDB(2, coff1);
    short8 a00 = RDA(0, coff0), a01 = RDA(0, coff1);
    short8 a10 = RDA(1, coff0), a11 = RDA(1, coff1);
    if (t < 11) {  // all next-tile staging in one clump: max cover before end-of-tile vmcnt(0)
      STAGEA(t + 1, 0); STAGEA(t + 1, 1);
      STAGEB(t + 1, 0); STAGEB(t + 1, 1); STAGEB(t + 1, 2);
    }
    __builtin_amdgcn_s_setprio(1);
    MFMA12(0, a00, a01, a10, a11);
    a00 = RDA(2, coff0); a01 = RDA(2, coff1);
    a10 = RDA(3, coff0); a11 = RDA(3, coff1);
    MFMA12(1, a00, a01, a10, a11);
    a00 = RDA(4, coff0); a01 = RDA(4, coff1);
    a10 = RDA(5, coff0); a11 = RDA(5, coff1);
    MFMA12(2, a00, a01, a10, a11);
    a00 = RDA(6, coff0); a01 = RDA(6, coff1);
    a10 = RDA(7, coff0); a11 = RDA(7, coff1);
    MFMA12(3, a00, a01, a10, a11);
    __builtin_amdgcn_s_setprio(0);
    asm volatile("s_waitcnt vmcnt(0)" ::: "memory");  // next tile landed; clobber pins LDS-read hoisting
    __builtin_amdgcn_s_barrier();                     // all waves' tile-t reads consumed before slot reuse
  }
#undef MFMA12
#undef RDA
#undef RDB
#undef STAGEA
#undef STAGEB

  if (MODE == 0) {
    // tile is entirely q (n0<768), k (768<=n0<1536) or v (n0>=1536): 768 = 4*192
    const bool sg = (n0 < 1536);
    const int colc = n0 + wn * 48;
    float jsum[3] = {0.f, 0.f, 0.f};
#pragma unroll
    for (int mi = 0; mi < 8; ++mi) {
      const int rowb = m0 + (wm << 7) + (mi << 4) + ((lane >> 4) << 2);
#pragma unroll
      for (int nj = 0; nj < 3; ++nj) {
        const int col = colc + (nj << 4) + r16;
        const float bcol = bias[col];
        if (sg) {
#pragma unroll
          for (int rg = 0; rg < 4; ++rg) {
            const float val = sigm(acc[mi][nj][rg] + bcol);
            jsum[nj] += val;
            qkvo[(size_t)(rowb + rg) * 2304 + col] = f2bfu(val);
          }
        } else {
#pragma unroll
          for (int rg = 0; rg < 4; ++rg)
            qkvo[(size_t)(rowb + rg) * 2304 + col] = f2bfu(acc[mi][nj][rg] + bcol);
        }
      }
    }
    if (sg) {
#pragma unroll
      for (int nj = 0; nj < 3; ++nj) {
        jsum[nj] += __shfl_xor(jsum[nj], 16, 64);
        jsum[nj] += __shfl_xor(jsum[nj], 32, 64);
      }
      if (lane < 16) {
        const int b768 = (m0 >> 12) * 768;
        float* sdst = (n0 >= 768) ? ksum : qsum;
        const int cb = colc - ((n0 >= 768) ? 768 : 0);
#pragma unroll
        for (int nj = 0; nj < 3; ++nj)
          atomicAdd(&sdst[b768 + cb + (nj << 4) + r16], jsum[nj]);
      }
    }
  } else {
#pragma unroll
    for (int mi = 0; mi < 8; ++mi) {
      const int rowb = m0 + (wm << 7) + (mi << 4) + ((lane >> 4) << 2);
#pragma unroll
      for (int nj = 0; nj < 3; ++nj) {
        const int col = n0 + wn * 48 + (nj << 4) + r16;
        const float bcol = bias[col];
#pragma unroll
        for (int rg = 0; rg < 4; ++rg)
          outf[(size_t)(rowb + rg) * 768 + col] = sigm(2.f * (acc[mi][nj][rg] + bcol));
      }
    }
  }
}

// ---------------- si/so + qsi/kso: 8-lane groups, 16B loads, 4-row ILP ----------------
__global__ __launch_bounds__(256) void k_flow1(
    const u16* __restrict__ qkv,
    const float* __restrict__ qsum, const float* __restrict__ ksum,
    float* __restrict__ si_out, float* __restrict__ qsi, float* __restrict__ kso)
{
  const int bh = blockIdx.x >> 3, sp = blockIdx.x & 7;
  const int tid = threadIdx.x;
  const int grp = tid >> 3;
  const int d0 = (tid & 7) << 3;
  const u16* base = qkv + (size_t)(bh / 12) * 4096 * 2304 + (bh % 12) * 64;

  float ke[8], qe[8];
#pragma unroll
  for (int u = 0; u < 8; ++u) {
    ke[u] = ksum[(bh << 6) + d0 + u] + EPSF;
    qe[u] = qsum[(bh << 6) + d0 + u] + EPSF;
  }
  float Sk = 0.f, Sq = 0.f;
#pragma unroll
  for (int u = 0; u < 8; ++u) { Sk += ke[u]; Sq += qe[u]; }
#pragma unroll
  for (int m = 1; m < 8; m <<= 1) { Sk += __shfl_xor(Sk, m, 64); Sq += __shfl_xor(Sq, m, 64); }
  const float cK = EPSF * Sk + EPSF;
  const float cQ = EPSF * Sq + EPSF;

  float aq[8], ak[8];
#pragma unroll
  for (int u = 0; u < 8; ++u) { aq[u] = 0.f; ak[u] = 0.f; }

  const int nbase = sp << 9;
#pragma unroll 4
  for (int it = 0; it < 16; ++it) {
    const int n = nbase + (it << 5) + grp;
    const u16* rp = base + (size_t)n * 2304 + d0;
    short8 q8 = *(const short8*)(rp);
    short8 k8 = *(const short8*)(rp + 768);
    float dq = 0.f, dk = 0.f;
#pragma unroll
    for (int u = 0; u < 8; ++u) {
      dq += us2f((u16)q8[u]) * ke[u];
      dk += us2f((u16)k8[u]) * qe[u];
    }
#pragma unroll
    for (int m = 1; m < 8; m <<= 1) { dq += __shfl_xor(dq, m, 64); dk += __shfl_xor(dk, m, 64); }
    const float si = 1.f / (dq + cK);
    const float so = 1.f / (dk + cQ);
    if ((tid & 7) == 0) si_out[(bh << 12) + n] = si;
#pragma unroll
    for (int u = 0; u < 8; ++u) {
      aq[u] += us2f((u16)q8[u]) * si;
      ak[u] += us2f((u16)k8[u]) * so;
    }
  }
  __shared__ float redq[32][68];
  __shared__ float redk[32][68];
#pragma unroll
  for (int u = 0; u < 8; ++u) { redq[grp][d0 + u] = aq[u]; redk[grp][d0 + u] = ak[u]; }
  __syncthreads();
  if (tid < 128) {
    const int which = tid >> 6, d = tid & 63;
    float s = 0.f;
    if (which == 0) {
#pragma unroll
      for (int g = 0; g < 32; ++g) s += redq[g][d];
      atomicAdd(&qsi[(bh << 6) + d], s);
    } else {
#pragma unroll
      for (int g = 0; g < 32; ++g) s += redk[g][d];
      atomicAdd(&kso[(bh << 6) + d], s);
    }
  }
}

// ---------------- fused kv (MFMA): e/sumexp inline, kvm[d][e] accumulate ----------------
__global__ __launch_bounds__(256) void k_fkv(
    const u16* __restrict__ qkv,
    const float* __restrict__ qsi,
    float* __restrict__ sumexp, float* __restrict__ kvm)
{
  __shared__ __align__(16) u16 smem[2 * 64 * 136];  // 34816 B; reused as f32 reduce buf
  u16* kT = smem;
  u16* vT = smem + 64 * 136;
  const int tid = threadIdx.x;
  const int bh = blockIdx.x >> 3, sp = blockIdx.x & 7;
  const int lane = tid & 63, wid = tid >> 6;
  const int r16 = lane & 15, g = lane >> 4;
  const u16* base = qkv + (size_t)(bh / 12) * 4096 * 2304 + (bh % 12) * 64;

  const int d0 = (tid & 7) << 3;
  float qie[8];
#pragma unroll
  for (int u = 0; u < 8; ++u) qie[u] = qsi[(bh << 6) + d0 + u] + EPSF;
  float Sq = qsi[(bh << 6) + lane] + EPSF;
#pragma unroll
  for (int m = 1; m < 64; m <<= 1) Sq += __shfl_xor(Sq, m, 64);
  const float cR = EPSF * Sq + EPSF;

  f32x4 acc[4][4];
#pragma unroll
  for (int i = 0; i < 4; ++i)
#pragma unroll
    for (int j = 0; j < 4; ++j) acc[i][j] = (f32x4){0.f, 0.f, 0.f, 0.f};

  const int nf = (wid << 5) + (g << 3);
  float esum = 0.f;

  for (int st = 0; st < 4; ++st) {
    const int nst = (sp << 9) + (st << 7);
    // issue all 4 row-pair loads first (ILP), then process
    short8 k8v[4], v8v[4];
#pragma unroll
    for (int i = 0; i < 4; ++i) {
      const int c = tid + (i << 8);
      const int nl = c >> 3;
      const u16* rp = base + (size_t)(nst + nl) * 2304 + d0;
      k8v[i] = *(const short8*)(rp + 768);
      v8v[i] = *(const short8*)(rp + 1536);
    }
#pragma unroll
    for (int i = 0; i < 4; ++i) {
      const int c = tid + (i << 8);
      const int nl = c >> 3;
      short8 k8 = k8v[i], v8 = v8v[i];
      float pcr = 0.f;
#pragma unroll
      for (int u = 0; u < 8; ++u) pcr += us2f((u16)k8[u]) * qie[u];
#pragma unroll
      for (int m = 1; m < 8; m <<= 1) pcr += __shfl_xor(pcr, m, 64);
      float cr = pcr + cR;
      cr = fminf(1.f, fmaxf(-1.f, cr));
      const float ev = __expf(cr);
      const int col = nl ^ (d0 & 56);
#pragma unroll
      for (int u = 0; u < 8; ++u) {
        kT[(d0 + u) * 136 + col] = f2bfu(us2f((u16)k8[u]) * ev);
        vT[(d0 + u) * 136 + col] = (u16)(unsigned short)v8[u];
      }
      if ((tid & 7) == 0) esum += ev;
    }
    __syncthreads();

    short8 af[4], bf[4];
#pragma unroll
    for (int mi = 0; mi < 4; ++mi) {
      const int row = (mi << 4) + r16;
      af[mi] = *(const short8*)&kT[row * 136 + (nf ^ (row & 56))];
    }
#pragma unroll
    for (int nj = 0; nj < 4; ++nj) {
      const int row = (nj << 4) + r16;
      bf[nj] = *(const short8*)&vT[row * 136 + (nf ^ (row & 56))];
    }
#pragma unroll
    for (int mi = 0; mi < 4; ++mi)
#pragma unroll
      for (int nj = 0; nj < 4; ++nj)
        acc[mi][nj] = __builtin_amdgcn_mfma_f32_16x16x32_bf16(af[mi], bf[nj], acc[mi][nj], 0, 0, 0);
    __syncthreads();
  }

  // cross-wave reduce (two 32-d halves through LDS) + coalesced atomics
  float* red = (float*)smem;
  float* kvb = kvm + ((size_t)bh << 12);
#pragma unroll
  for (int half = 0; half < 2; ++half) {
#pragma unroll
    for (int m2 = 0; m2 < 2; ++m2) {
      const int mi = (half << 1) + m2;
#pragma unroll
      for (int nj = 0; nj < 4; ++nj)
#pragma unroll
        for (int rg = 0; rg < 4; ++rg)
          red[(wid << 11) + (((m2 << 4) + (g << 2) + rg) << 6) + (nj << 4) + r16] = acc[mi][nj][rg];
    }
    __syncthreads();
    const int base2 = tid << 3;
#pragma unroll
    for (int u2 = 0; u2 < 2; ++u2) {
      const int o = base2 + (u2 << 2);
      float4 s0 = *(const float4*)&red[o];
      float4 s1 = *(const float4*)&red[2048 + o];
      float4 s2 = *(const float4*)&red[4096 + o];
      float4 s3 = *(const float4*)&red[6144 + o];
      s0.x += s1.x + s2.x + s3.x;
      s0.y += s1.y + s2.y + s3.y;
      s0.z += s1.z + s2.z + s3.z;
      s0.w += s1.w + s2.w + s3.w;
      const int gi = (half << 11) + o;
      atomicAdd(&kvb[gi + 0], s0.x);
      atomicAdd(&kvb[gi + 1], s0.y);
      atomicAdd(&kvb[gi + 2], s0.z);
      atomicAdd(&kvb[gi + 3], s0.w);
    }
    __syncthreads();
  }

  esum += __shfl_xor(esum, 8, 64);
  esum += __shfl_xor(esum, 16, 64);
  esum += __shfl_xor(esum, 32, 64);
  if (lane == 0) atomicAdd(&sumexp[bh], esum);
}

// ---------------- x_update = (q @ kv) * m[n] * scale; m computed inline from q,kso,si ----------------
__global__ __launch_bounds__(256) void k_xup(
    const u16* __restrict__ qkv, const float* __restrict__ kvm,
    const float* __restrict__ si_arr, const float* __restrict__ kso,
    const float* __restrict__ sumexp,
    u16* __restrict__ attn)
{
  const int bh = blockIdx.y;
  const int n0 = blockIdx.x << 7;
  const int b = bh / 12, h = bh % 12;
  __shared__ __align__(16) u16 qs[128 * 72];
  __shared__ __align__(16) u16 kvs[64 * 72];
  __shared__ float m_lds[128];
  const int tid = threadIdx.x, lane = tid & 63, wid = tid >> 6;
  const int d0c = (tid & 7) << 3;

  float soe[8];
#pragma unroll
  for (int u = 0; u < 8; ++u) soe[u] = kso[(bh << 6) + d0c + u] + EPSF;
  float Ss = 0.f;
#pragma unroll
  for (int u = 0; u < 8; ++u) Ss += soe[u];
#pragma unroll
  for (int m = 1; m < 8; m <<= 1) Ss += __shfl_xor(Ss, m, 64);
  const float cS = EPSF * Ss + EPSF;

  const u16* qg = qkv + (size_t)b * 4096 * 2304 + (size_t)n0 * 2304 + h * 64;
#pragma unroll
  for (int i = 0; i < 4; ++i) {
    const int c = tid + (i << 8);
    const int nl = c >> 3, d0 = (c & 7) << 3;
    short8 q8 = *(const short8*)(qg + (size_t)nl * 2304 + d0);
    *(short8*)&qs[nl * 72 + d0] = q8;
    float pcs = 0.f;
#pragma unroll
    for (int u = 0; u < 8; ++u) pcs += us2f((u16)q8[u]) * soe[u];
#pragma unroll
    for (int m = 1; m < 8; m <<= 1) pcs += __shfl_xor(pcs, m, 64);
    if ((tid & 7) == 0)
      m_lds[nl] = si_arr[((size_t)bh << 12) + n0 + nl] * sigm(pcs + cS);
  }
  const float* kvg = kvm + ((size_t)bh << 12);
#pragma unroll
  for (int i = 0; i < 4; ++i) {
    const int idx = (tid << 2) + (i << 10);
    const int d = idx >> 6, e0 = idx & 63;
    float4 vv = *(const float4*)(kvg + idx);
    kvs[(e0 + 0) * 72 + d] = f2bfu(vv.x);
    kvs[(e0 + 1) * 72 + d] = f2bfu(vv.y);
    kvs[(e0 + 2) * 72 + d] = f2bfu(vv.z);
    kvs[(e0 + 3) * 72 + d] = f2bfu(vv.w);
  }
  __syncthreads();
  const float scale = 4096.f / sumexp[bh];
  const int r16 = lane & 15, kg8 = (lane >> 4) << 3;
  f32x4 acc[2][4];
#pragma unroll
  for (int i = 0; i < 2; ++i)
#pragma unroll
    for (int j = 0; j < 4; ++j) acc[i][j] = (f32x4){0.f, 0.f, 0.f, 0.f};
#pragma unroll
  for (int kk = 0; kk < 2; ++kk) {
    short8 af[2], bfv[4];
#pragma unroll
    for (int mi = 0; mi < 2; ++mi)
      af[mi] = *(const short8*)&qs[((wid << 5) + (mi << 4) + r16) * 72 + (kk << 5) + kg8];
#pragma unroll
    for (int nj = 0; nj < 4; ++nj)
      bfv[nj] = *(const short8*)&kvs[((nj << 4) + r16) * 72 + (kk << 5) + kg8];
#pragma unroll
    for (int mi = 0; mi < 2; ++mi)
#pragma unroll
      for (int nj = 0; nj < 4; ++nj)
        acc[mi][nj] = __builtin_amdgcn_mfma_f32_16x16x32_bf16(af[mi], bfv[nj], acc[mi][nj], 0, 0, 0);
  }
#pragma unroll
  for (int mi = 0; mi < 2; ++mi) {
#pragma unroll
    for (int rg = 0; rg < 4; ++rg) {
      const int nloc = (wid << 5) + (mi << 4) + ((lane >> 4) << 2) + rg;
      const int n = n0 + nloc;
      const float mult = m_lds[nloc] * scale;
#pragma unroll
      for (int nj = 0; nj < 4; ++nj) {
        const int e = (nj << 4) + r16;
        attn[((size_t)(b * 4096 + n)) * 768 + (h << 6) + e] = f2bfu(acc[mi][nj][rg] * mult);
      }
    }
  }
}

extern "C" void kernel_launch(void* const* d_in, const int* in_sizes, int n_in,
                              void* d_out, int out_size, void* d_ws, size_t ws_size,
                              hipStream_t stream)
{
  (void)in_sizes; (void)n_in; (void)out_size; (void)ws_size;
  const float* x     = (const float*)d_in[0];
  const float* Wqkv  = (const float*)d_in[1];
  const float* bqkv  = (const float*)d_in[2];
  const float* Wproj = (const float*)d_in[3];
  const float* bproj = (const float*)d_in[4];
  float* out = (float*)d_out;

  char* ws = (char*)d_ws;
  size_t off = 0;
  auto alloc = [&](size_t bytes) -> char* {
    char* p = ws + off;
    off += (bytes + 255) & ~(size_t)255;
    return p;
  };
  u16* qkv  = (u16*)alloc(150994944);      // [32768][2304] bf16 flat (q|k|v)
  u16* xbf  = (u16*)alloc(50331648);       // x bf16; reused as attn output
  u16* WqT  = (u16*)alloc(3538944);        // [2304][768] bf16
  u16* WpT  = (u16*)alloc(1179648);        // [768][768] bf16
  float* si = (float*)alloc(1572864);      // [B*H][N]
  char* zbase = ws + off;
  float* qsum   = (float*)alloc(24576);
  float* ksum   = (float*)alloc(24576);
  float* qsi    = (float*)alloc(24576);
  float* kso    = (float*)alloc(24576);
  float* sumexp = (float*)alloc(512);
  float* kvm    = (float*)alloc(1572864);  // [B*H][64 d][64 e] f32
  const size_t zbytes = (size_t)((ws + off) - zbase);

  hipMemsetAsync(zbase, 0, zbytes, stream);
  k_prep<<<26880, 256, 0, stream>>>(x, xbf, Wqkv, WqT, Wproj, WpT);
  k_gemm<0><<<dim3(12, 128), 512, 0, stream>>>(xbf, WqT, bqkv, qkv, qsum, ksum, nullptr);
  k_flow1<<<768, 256, 0, stream>>>(qkv, qsum, ksum, si, qsi, kso);
  k_fkv<<<768, 256, 0, stream>>>(qkv, qsi, sumexp, kvm);
  k_xup<<<dim3(32, 96), 256, 0, stream>>>(qkv, kvm, si, kso, sumexp, xbf);
  k_gemm<1><<<dim3(4, 128), 512, 0, stream>>>(xbf, WpT, bproj, nullptr, nullptr, nullptr, out);
}

// Round 18
// 364.722 us; speedup vs baseline: 1.0148x; 1.0148x over previous
//
#include <hip/hip_runtime.h>
#include <stdint.h>

#define EPSF 1e-6f

typedef unsigned short u16;
typedef __attribute__((ext_vector_type(8))) short short8;
typedef __attribute__((ext_vector_type(4))) float f32x4;

__device__ __forceinline__ float us2f(u16 u) {
  union { float f; unsigned int i; } c; c.i = ((unsigned int)u) << 16; return c.f;
}
__device__ __forceinline__ u16 f2bfu(float f) {
  union { float f; unsigned int i; } c; c.f = f;
  unsigned int i = c.i;
  return (u16)((i + 0x7FFFu + ((i >> 16) & 1u)) >> 16);
}
__device__ __forceinline__ float sigm(float x) { return 1.f / (1.f + __expf(-x)); }

typedef __attribute__((address_space(3))) unsigned int lds_u32;
typedef const __attribute__((address_space(1))) unsigned int glb_u32;
__device__ __forceinline__ void gl_lds16(const u16* g, u16* l) {
  __builtin_amdgcn_global_load_lds((glb_u32*)g, (lds_u32*)l, 16, 0, 0);
}

// ---------------- fused prep: x cvt (blocks 0..24575) + W transposes ----------------
__global__ void k_prep(const float* __restrict__ x, u16* __restrict__ xbf,
                       const float* __restrict__ Wqkv, u16* __restrict__ WqT,
                       const float* __restrict__ Wproj, u16* __restrict__ WpT) {
  __shared__ float tile[32][33];
  const int b = blockIdx.x;
  if (b < 24576) {
    const int i = b * 256 + threadIdx.x;
    float4 v = ((const float4*)x)[i];
    ushort4 o;
    o.x = f2bfu(v.x); o.y = f2bfu(v.y); o.z = f2bfu(v.z); o.w = f2bfu(v.w);
    ((ushort4*)xbf)[i] = o;
    return;
  }
  const float* in; u16* out; int R, C, bx, by;
  if (b < 24576 + 1728) {
    const int id = b - 24576; in = Wqkv; out = WqT; R = 768; C = 2304; bx = id % 72; by = id / 72;
  } else {
    const int id = b - 26304; in = Wproj; out = WpT; R = 768; C = 768; bx = id % 24; by = id / 24;
  }
  const int tx = threadIdx.x & 31, ty = threadIdx.x >> 5;
  const int c0 = bx << 5, r0 = by << 5;
  for (int i = ty; i < 32; i += 8) tile[i][tx] = in[(size_t)(r0 + i) * C + c0 + tx];
  __syncthreads();
  for (int i = ty; i < 32; i += 8) out[(size_t)(c0 + i) * R + r0 + tx] = f2bfu(tile[tx][i]);
}

// ---------------- GEMM: 256x192 tile, 8 waves, BK=64, 1 barrier/tile (round-16 exact) ----------------
// Measured best (148.5us, MfmaUtil 35.3): split staging (STAGEA before MFMA0, STAGEB after,
// setprio toggle between) — round-17's clumped variant regressed +11us. Single barrier/tile;
// tile handoff = vmcnt(0) memory clobber + s_barrier. Bit-identical math.
template <int MODE>
__global__ __launch_bounds__(512, 1) void k_gemm(
    const u16* __restrict__ A, const u16* __restrict__ BT,
    const float* __restrict__ bias,
    u16* __restrict__ qkvo, float* __restrict__ qsum, float* __restrict__ ksum,
    float* __restrict__ outf)
{
  __shared__ __align__(16) u16 smem[57344];  // 112 KB
  const int tid = threadIdx.x;
  const int lane = tid & 63;
  const int wid = tid >> 6;           // 0..7
  const int wm = wid >> 2, wn = wid & 3;
  // bijective XCD swizzle (nwg % 8 == 0 for both grids)
  const int nx = gridDim.x;
  int lid = blockIdx.y * nx + blockIdx.x;
  const int q8 = (nx * gridDim.y) >> 3;
  lid = (lid & 7) * q8 + (lid >> 3);
  const int m0 = (lid / nx) << 8;
  const int n0 = (lid % nx) * 192;

  const int rowL0 = tid >> 3;                      // 0..63
  const int gc = (tid & 7) ^ (rowL0 & 7);
  const u16* gA = A  + (size_t)(m0 + rowL0) * 768 + (gc << 3);
  const u16* gB = BT + (size_t)(n0 + rowL0) * 768 + (gc << 3);

  const int r16 = lane & 15;
  const int sgrp = lane >> 4;
  const int xk = r16 & 7;
  const int coff0 = ((sgrp) ^ xk) << 3;            // kslot 0 chunk offset (elems)
  const int coff1 = ((4 + sgrp) ^ xk) << 3;        // kslot 1
  int offB[3];
#pragma unroll
  for (int nj = 0; nj < 3; ++nj) {
    const int ub = wn * 48 + (nj << 4);            // 16-row band base (never straddles 64)
    offB[nj] = ((ub >> 6) << 12) + (((ub & 63) + r16) << 6);
  }

  f32x4 acc[8][3];
#pragma unroll
  for (int i = 0; i < 8; ++i)
#pragma unroll
    for (int j = 0; j < 3; ++j) acc[i][j] = (f32x4){0.f, 0.f, 0.f, 0.f};

#define STAGEA(tt, y)                                                         \
  do {                                                                        \
    u16* dst = &smem[(((tt) & 1) * 28672) + ((y) << 13) + (tid << 3)];        \
    const u16* s = gA + (size_t)(y) * 98304 + (tt) * 64;                      \
    gl_lds16(s, dst);                                                         \
    gl_lds16(s + 49152, dst + 4096);                                          \
  } while (0)

#define STAGEB(tt, u)                                                         \
  do {                                                                        \
    u16* dst = &smem[(((tt) & 1) * 28672) + 16384 + ((u) << 12) + (tid << 3)];\
    gl_lds16(gB + (size_t)(u) * 49152 + (tt) * 64, dst);                      \
  } while (0)

#define RDA(mi, co) (*(const short8*)(pa + ((((mi) << 4) + r16) << 6) + (co)))
#define RDB(nj, co) (*(const short8*)(pb + offB[nj] + (co)))

#define MFMA12(P, A00, A01, A10, A11)                                                               \
  do {                                                                                              \
    acc[2*(P)  ][0] = __builtin_amdgcn_mfma_f32_16x16x32_bf16(A00, bf[0][0], acc[2*(P)  ][0],0,0,0);\
    acc[2*(P)  ][1] = __builtin_amdgcn_mfma_f32_16x16x32_bf16(A00, bf[1][0], acc[2*(P)  ][1],0,0,0);\
    acc[2*(P)  ][2] = __builtin_amdgcn_mfma_f32_16x16x32_bf16(A00, bf[2][0], acc[2*(P)  ][2],0,0,0);\
    acc[2*(P)+1][0] = __builtin_amdgcn_mfma_f32_16x16x32_bf16(A10, bf[0][0], acc[2*(P)+1][0],0,0,0);\
    acc[2*(P)+1][1] = __builtin_amdgcn_mfma_f32_16x16x32_bf16(A10, bf[1][0], acc[2*(P)+1][1],0,0,0);\
    acc[2*(P)+1][2] = __builtin_amdgcn_mfma_f32_16x16x32_bf16(A10, bf[2][0], acc[2*(P)+1][2],0,0,0);\
    acc[2*(P)  ][0] = __builtin_amdgcn_mfma_f32_16x16x32_bf16(A01, bf[0][1], acc[2*(P)  ][0],0,0,0);\
    acc[2*(P)  ][1] = __builtin_amdgcn_mfma_f32_16x16x32_bf16(A01, bf[1][1], acc[2*(P)  ][1],0,0,0);\
    acc[2*(P)  ][2] = __builtin_amdgcn_mfma_f32_16x16x32_bf16(A01, bf[2][1], acc[2*(P)  ][2],0,0,0);\
    acc[2*(P)+1][0] = __builtin_amdgcn_mfma_f32_16x16x32_bf16(A11, bf[0][1], acc[2*(P)+1][0],0,0,0);\
    acc[2*(P)+1][1] = __builtin_amdgcn_mfma_f32_16x16x32_bf16(A11, bf[1][1], acc[2*(P)+1][1],0,0,0);\
    acc[2*(P)+1][2] = __builtin_amdgcn_mfma_f32_16x16x32_bf16(A11, bf[2][1], acc[2*(P)+1][2],0,0,0);\
  } while (0)

  STAGEA(0, 0); STAGEA(0, 1); STAGEB(0, 0); STAGEB(0, 1); STAGEB(0, 2);
  asm volatile("s_waitcnt vmcnt(0)" ::: "memory");
  __builtin_amdgcn_s_barrier();

  for (int t = 0; t < 12; ++t) {
    const u16* pa = &smem[(t & 1) * 28672 + (wm << 13)];
    const u16* pb = &smem[(t & 1) * 28672 + 16384];
    short8 bf[3][2];
    bf[0][0] = RDB(0, coff0); bf[0][1] = RDB(0, coff1);
    bf[1][0] = RDB(1, coff0); bf[1][1] = RDB(1, coff1);
    bf[2][0] = RDB(2, coff0); bf[2][1] = RDB(2, coff1);
    short8 a00 = RDA(0, coff0), a01 = RDA(0, coff1);
    short8 a10 = RDA(1, coff0), a11 = RDA(1, coff1);
    if (t < 11) { STAGEA(t + 1, 0); STAGEA(t + 1, 1); }
    __builtin_amdgcn_s_setprio(1);
    MFMA12(0, a00, a01, a10, a11);
    a00 = RDA(2, coff0); a01 = RDA(2, coff1);
    a10 = RDA(3, coff0); a11 = RDA(3, coff1);
    __builtin_amdgcn_s_setprio(0);
    if (t < 11) { STAGEB(t + 1, 0); STAGEB(t + 1, 1); STAGEB(t + 1, 2); }
    __builtin_amdgcn_s_setprio(1);
    MFMA12(1, a00, a01, a10, a11);
    a00 = RDA(4, coff0); a01 = RDA(4, coff1);
    a10 = RDA(5, coff0); a11 = RDA(5, coff1);
    MFMA12(2, a00, a01, a10, a11);
    a00 = RDA(6, coff0); a01 = RDA(6, coff1);
    a10 = RDA(7, coff0); a11 = RDA(7, coff1);
    MFMA12(3, a00, a01, a10, a11);
    __builtin_amdgcn_s_setprio(0);
    asm volatile("s_waitcnt vmcnt(0)" ::: "memory");  // next tile landed; clobber pins LDS-read hoisting
    __builtin_amdgcn_s_barrier();                     // all waves' tile-t reads consumed before slot reuse
  }
#undef MFMA12
#undef RDA
#undef RDB
#undef STAGEA
#undef STAGEB

  if (MODE == 0) {
    // tile is entirely q (n0<768), k (768<=n0<1536) or v (n0>=1536): 768 = 4*192
    const bool sg = (n0 < 1536);
    const int colc = n0 + wn * 48;
    float jsum[3] = {0.f, 0.f, 0.f};
#pragma unroll
    for (int mi = 0; mi < 8; ++mi) {
      const int rowb = m0 + (wm << 7) + (mi << 4) + ((lane >> 4) << 2);
#pragma unroll
      for (int nj = 0; nj < 3; ++nj) {
        const int col = colc + (nj << 4) + r16;
        const float bcol = bias[col];
        if (sg) {
#pragma unroll
          for (int rg = 0; rg < 4; ++rg) {
            const float val = sigm(acc[mi][nj][rg] + bcol);
            jsum[nj] += val;
            qkvo[(size_t)(rowb + rg) * 2304 + col] = f2bfu(val);
          }
        } else {
#pragma unroll
          for (int rg = 0; rg < 4; ++rg)
            qkvo[(size_t)(rowb + rg) * 2304 + col] = f2bfu(acc[mi][nj][rg] + bcol);
        }
      }
    }
    if (sg) {
#pragma unroll
      for (int nj = 0; nj < 3; ++nj) {
        jsum[nj] += __shfl_xor(jsum[nj], 16, 64);
        jsum[nj] += __shfl_xor(jsum[nj], 32, 64);
      }
      if (lane < 16) {
        const int b768 = (m0 >> 12) * 768;
        float* sdst = (n0 >= 768) ? ksum : qsum;
        const int cb = colc - ((n0 >= 768) ? 768 : 0);
#pragma unroll
        for (int nj = 0; nj < 3; ++nj)
          atomicAdd(&sdst[b768 + cb + (nj << 4) + r16], jsum[nj]);
      }
    }
  } else {
#pragma unroll
    for (int mi = 0; mi < 8; ++mi) {
      const int rowb = m0 + (wm << 7) + (mi << 4) + ((lane >> 4) << 2);
#pragma unroll
      for (int nj = 0; nj < 3; ++nj) {
        const int col = n0 + wn * 48 + (nj << 4) + r16;
        const float bcol = bias[col];
#pragma unroll
        for (int rg = 0; rg < 4; ++rg)
          outf[(size_t)(rowb + rg) * 768 + col] = sigm(2.f * (acc[mi][nj][rg] + bcol));
      }
    }
  }
}

// ---------------- si/so + qsi/kso: 8-lane groups, 16B loads, 4-row ILP ----------------
__global__ __launch_bounds__(256) void k_flow1(
    const u16* __restrict__ qkv,
    const float* __restrict__ qsum, const float* __restrict__ ksum,
    float* __restrict__ si_out, float* __restrict__ qsi, float* __restrict__ kso)
{
  const int bh = blockIdx.x >> 3, sp = blockIdx.x & 7;
  const int tid = threadIdx.x;
  const int grp = tid >> 3;
  const int d0 = (tid & 7) << 3;
  const u16* base = qkv + (size_t)(bh / 12) * 4096 * 2304 + (bh % 12) * 64;

  float ke[8], qe[8];
#pragma unroll
  for (int u = 0; u < 8; ++u) {
    ke[u] = ksum[(bh << 6) + d0 + u] + EPSF;
    qe[u] = qsum[(bh << 6) + d0 + u] + EPSF;
  }
  float Sk = 0.f, Sq = 0.f;
#pragma unroll
  for (int u = 0; u < 8; ++u) { Sk += ke[u]; Sq += qe[u]; }
#pragma unroll
  for (int m = 1; m < 8; m <<= 1) { Sk += __shfl_xor(Sk, m, 64); Sq += __shfl_xor(Sq, m, 64); }
  const float cK = EPSF * Sk + EPSF;
  const float cQ = EPSF * Sq + EPSF;

  float aq[8], ak[8];
#pragma unroll
  for (int u = 0; u < 8; ++u) { aq[u] = 0.f; ak[u] = 0.f; }

  const int nbase = sp << 9;
#pragma unroll 4
  for (int it = 0; it < 16; ++it) {
    const int n = nbase + (it << 5) + grp;
    const u16* rp = base + (size_t)n * 2304 + d0;
    short8 q8 = *(const short8*)(rp);
    short8 k8 = *(const short8*)(rp + 768);
    float dq = 0.f, dk = 0.f;
#pragma unroll
    for (int u = 0; u < 8; ++u) {
      dq += us2f((u16)q8[u]) * ke[u];
      dk += us2f((u16)k8[u]) * qe[u];
    }
#pragma unroll
    for (int m = 1; m < 8; m <<= 1) { dq += __shfl_xor(dq, m, 64); dk += __shfl_xor(dk, m, 64); }
    const float si = 1.f / (dq + cK);
    const float so = 1.f / (dk + cQ);
    if ((tid & 7) == 0) si_out[(bh << 12) + n] = si;
#pragma unroll
    for (int u = 0; u < 8; ++u) {
      aq[u] += us2f((u16)q8[u]) * si;
      ak[u] += us2f((u16)k8[u]) * so;
    }
  }
  __shared__ float redq[32][68];
  __shared__ float redk[32][68];
#pragma unroll
  for (int u = 0; u < 8; ++u) { redq[grp][d0 + u] = aq[u]; redk[grp][d0 + u] = ak[u]; }
  __syncthreads();
  if (tid < 128) {
    const int which = tid >> 6, d = tid & 63;
    float s = 0.f;
    if (which == 0) {
#pragma unroll
      for (int g = 0; g < 32; ++g) s += redq[g][d];
      atomicAdd(&qsi[(bh << 6) + d], s);
    } else {
#pragma unroll
      for (int g = 0; g < 32; ++g) s += redk[g][d];
      atomicAdd(&kso[(bh << 6) + d], s);
    }
  }
}

// ---------------- fused kv (MFMA): e/sumexp inline, kvm[d][e] accumulate ----------------
__global__ __launch_bounds__(256) void k_fkv(
    const u16* __restrict__ qkv,
    const float* __restrict__ qsi,
    float* __restrict__ sumexp, float* __restrict__ kvm)
{
  __shared__ __align__(16) u16 smem[2 * 64 * 136];  // 34816 B; reused as f32 reduce buf
  u16* kT = smem;
  u16* vT = smem + 64 * 136;
  const int tid = threadIdx.x;
  const int bh = blockIdx.x >> 3, sp = blockIdx.x & 7;
  const int lane = tid & 63, wid = tid >> 6;
  const int r16 = lane & 15, g = lane >> 4;
  const u16* base = qkv + (size_t)(bh / 12) * 4096 * 2304 + (bh % 12) * 64;

  const int d0 = (tid & 7) << 3;
  float qie[8];
#pragma unroll
  for (int u = 0; u < 8; ++u) qie[u] = qsi[(bh << 6) + d0 + u] + EPSF;
  float Sq = qsi[(bh << 6) + lane] + EPSF;
#pragma unroll
  for (int m = 1; m < 64; m <<= 1) Sq += __shfl_xor(Sq, m, 64);
  const float cR = EPSF * Sq + EPSF;

  f32x4 acc[4][4];
#pragma unroll
  for (int i = 0; i < 4; ++i)
#pragma unroll
    for (int j = 0; j < 4; ++j) acc[i][j] = (f32x4){0.f, 0.f, 0.f, 0.f};

  const int nf = (wid << 5) + (g << 3);
  float esum = 0.f;

  for (int st = 0; st < 4; ++st) {
    const int nst = (sp << 9) + (st << 7);
    // issue all 4 row-pair loads first (ILP), then process
    short8 k8v[4], v8v[4];
#pragma unroll
    for (int i = 0; i < 4; ++i) {
      const int c = tid + (i << 8);
      const int nl = c >> 3;
      const u16* rp = base + (size_t)(nst + nl) * 2304 + d0;
      k8v[i] = *(const short8*)(rp + 768);
      v8v[i] = *(const short8*)(rp + 1536);
    }
#pragma unroll
    for (int i = 0; i < 4; ++i) {
      const int c = tid + (i << 8);
      const int nl = c >> 3;
      short8 k8 = k8v[i], v8 = v8v[i];
      float pcr = 0.f;
#pragma unroll
      for (int u = 0; u < 8; ++u) pcr += us2f((u16)k8[u]) * qie[u];
#pragma unroll
      for (int m = 1; m < 8; m <<= 1) pcr += __shfl_xor(pcr, m, 64);
      float cr = pcr + cR;
      cr = fminf(1.f, fmaxf(-1.f, cr));
      const float ev = __expf(cr);
      const int col = nl ^ (d0 & 56);
#pragma unroll
      for (int u = 0; u < 8; ++u) {
        kT[(d0 + u) * 136 + col] = f2bfu(us2f((u16)k8[u]) * ev);
        vT[(d0 + u) * 136 + col] = (u16)(unsigned short)v8[u];
      }
      if ((tid & 7) == 0) esum += ev;
    }
    __syncthreads();

    short8 af[4], bf[4];
#pragma unroll
    for (int mi = 0; mi < 4; ++mi) {
      const int row = (mi << 4) + r16;
      af[mi] = *(const short8*)&kT[row * 136 + (nf ^ (row & 56))];
    }
#pragma unroll
    for (int nj = 0; nj < 4; ++nj) {
      const int row = (nj << 4) + r16;
      bf[nj] = *(const short8*)&vT[row * 136 + (nf ^ (row & 56))];
    }
#pragma unroll
    for (int mi = 0; mi < 4; ++mi)
#pragma unroll
      for (int nj = 0; nj < 4; ++nj)
        acc[mi][nj] = __builtin_amdgcn_mfma_f32_16x16x32_bf16(af[mi], bf[nj], acc[mi][nj], 0, 0, 0);
    __syncthreads();
  }

  // cross-wave reduce (two 32-d halves through LDS) + coalesced atomics
  float* red = (float*)smem;
  float* kvb = kvm + ((size_t)bh << 12);
#pragma unroll
  for (int half = 0; half < 2; ++half) {
#pragma unroll
    for (int m2 = 0; m2 < 2; ++m2) {
      const int mi = (half << 1) + m2;
#pragma unroll
      for (int nj = 0; nj < 4; ++nj)
#pragma unroll
        for (int rg = 0; rg < 4; ++rg)
          red[(wid << 11) + (((m2 << 4) + (g << 2) + rg) << 6) + (nj << 4) + r16] = acc[mi][nj][rg];
    }
    __syncthreads();
    const int base2 = tid << 3;
#pragma unroll
    for (int u2 = 0; u2 < 2; ++u2) {
      const int o = base2 + (u2 << 2);
      float4 s0 = *(const float4*)&red[o];
      float4 s1 = *(const float4*)&red[2048 + o];
      float4 s2 = *(const float4*)&red[4096 + o];
      float4 s3 = *(const float4*)&red[6144 + o];
      s0.x += s1.x + s2.x + s3.x;
      s0.y += s1.y + s2.y + s3.y;
      s0.z += s1.z + s2.z + s3.z;
      s0.w += s1.w + s2.w + s3.w;
      const int gi = (half << 11) + o;
      atomicAdd(&kvb[gi + 0], s0.x);
      atomicAdd(&kvb[gi + 1], s0.y);
      atomicAdd(&kvb[gi + 2], s0.z);
      atomicAdd(&kvb[gi + 3], s0.w);
    }
    __syncthreads();
  }

  esum += __shfl_xor(esum, 8, 64);
  esum += __shfl_xor(esum, 16, 64);
  esum += __shfl_xor(esum, 32, 64);
  if (lane == 0) atomicAdd(&sumexp[bh], esum);
}

// ---------------- x_update = (q @ kv) * m[n] * scale; m computed inline from q,kso,si ----------------
__global__ __launch_bounds__(256) void k_xup(
    const u16* __restrict__ qkv, const float* __restrict__ kvm,
    const float* __restrict__ si_arr, const float* __restrict__ kso,
    const float* __restrict__ sumexp,
    u16* __restrict__ attn)
{
  const int bh = blockIdx.y;
  const int n0 = blockIdx.x << 7;
  const int b = bh / 12, h = bh % 12;
  __shared__ __align__(16) u16 qs[128 * 72];
  __shared__ __align__(16) u16 kvs[64 * 72];
  __shared__ float m_lds[128];
  const int tid = threadIdx.x, lane = tid & 63, wid = tid >> 6;
  const int d0c = (tid & 7) << 3;

  float soe[8];
#pragma unroll
  for (int u = 0; u < 8; ++u) soe[u] = kso[(bh << 6) + d0c + u] + EPSF;
  float Ss = 0.f;
#pragma unroll
  for (int u = 0; u < 8; ++u) Ss += soe[u];
#pragma unroll
  for (int m = 1; m < 8; m <<= 1) Ss += __shfl_xor(Ss, m, 64);
  const float cS = EPSF * Ss + EPSF;

  const u16* qg = qkv + (size_t)b * 4096 * 2304 + (size_t)n0 * 2304 + h * 64;
#pragma unroll
  for (int i = 0; i < 4; ++i) {
    const int c = tid + (i << 8);
    const int nl = c >> 3, d0 = (c & 7) << 3;
    short8 q8 = *(const short8*)(qg + (size_t)nl * 2304 + d0);
    *(short8*)&qs[nl * 72 + d0] = q8;
    float pcs = 0.f;
#pragma unroll
    for (int u = 0; u < 8; ++u) pcs += us2f((u16)q8[u]) * soe[u];
#pragma unroll
    for (int m = 1; m < 8; m <<= 1) pcs += __shfl_xor(pcs, m, 64);
    if ((tid & 7) == 0)
      m_lds[nl] = si_arr[((size_t)bh << 12) + n0 + nl] * sigm(pcs + cS);
  }
  const float* kvg = kvm + ((size_t)bh << 12);
#pragma unroll
  for (int i = 0; i < 4; ++i) {
    const int idx = (tid << 2) + (i << 10);
    const int d = idx >> 6, e0 = idx & 63;
    float4 vv = *(const float4*)(kvg + idx);
    kvs[(e0 + 0) * 72 + d] = f2bfu(vv.x);
    kvs[(e0 + 1) * 72 + d] = f2bfu(vv.y);
    kvs[(e0 + 2) * 72 + d] = f2bfu(vv.z);
    kvs[(e0 + 3) * 72 + d] = f2bfu(vv.w);
  }
  __syncthreads();
  const float scale = 4096.f / sumexp[bh];
  const int r16 = lane & 15, kg8 = (lane >> 4) << 3;
  f32x4 acc[2][4];
#pragma unroll
  for (int i = 0; i < 2; ++i)
#pragma unroll
    for (int j = 0; j < 4; ++j) acc[i][j] = (f32x4){0.f, 0.f, 0.f, 0.f};
#pragma unroll
  for (int kk = 0; kk < 2; ++kk) {
    short8 af[2], bfv[4];
#pragma unroll
    for (int mi = 0; mi < 2; ++mi)
      af[mi] = *(const short8*)&qs[((wid << 5) + (mi << 4) + r16) * 72 + (kk << 5) + kg8];
#pragma unroll
    for (int nj = 0; nj < 4; ++nj)
      bfv[nj] = *(const short8*)&kvs[((nj << 4) + r16) * 72 + (kk << 5) + kg8];
#pragma unroll
    for (int mi = 0; mi < 2; ++mi)
#pragma unroll
      for (int nj = 0; nj < 4; ++nj)
        acc[mi][nj] = __builtin_amdgcn_mfma_f32_16x16x32_bf16(af[mi], bfv[nj], acc[mi][nj], 0, 0, 0);
  }
#pragma unroll
  for (int mi = 0; mi < 2; ++mi) {
#pragma unroll
    for (int rg = 0; rg < 4; ++rg) {
      const int nloc = (wid << 5) + (mi << 4) + ((lane >> 4) << 2) + rg;
      const int n = n0 + nloc;
      const float mult = m_lds[nloc] * scale;
#pragma unroll
      for (int nj = 0; nj < 4; ++nj) {
        const int e = (nj << 4) + r16;
        attn[((size_t)(b * 4096 + n)) * 768 + (h << 6) + e] = f2bfu(acc[mi][nj][rg] * mult);
      }
    }
  }
}

extern "C" void kernel_launch(void* const* d_in, const int* in_sizes, int n_in,
                              void* d_out, int out_size, void* d_ws, size_t ws_size,
                              hipStream_t stream)
{
  (void)in_sizes; (void)n_in; (void)out_size; (void)ws_size;
  const float* x     = (const float*)d_in[0];
  const float* Wqkv  = (const float*)d_in[1];
  const float* bqkv  = (const float*)d_in[2];
  const float* Wproj = (const float*)d_in[3];
  const float* bproj = (const float*)d_in[4];
  float* out = (float*)d_out;

  char* ws = (char*)d_ws;
  size_t off = 0;
  auto alloc = [&](size_t bytes) -> char* {
    char* p = ws + off;
    off += (bytes + 255) & ~(size_t)255;
    return p;
  };
  u16* qkv  = (u16*)alloc(150994944);      // [32768][2304] bf16 flat (q|k|v)
  u16* xbf  = (u16*)alloc(50331648);       // x bf16; reused as attn output
  u16* WqT  = (u16*)alloc(3538944);        // [2304][768] bf16
  u16* WpT  = (u16*)alloc(1179648);        // [768][768] bf16
  float* si = (float*)alloc(1572864);      // [B*H][N]
  char* zbase = ws + off;
  float* qsum   = (float*)alloc(24576);
  float* ksum   = (float*)alloc(24576);
  float* qsi    = (float*)alloc(24576);
  float* kso    = (float*)alloc(24576);
  float* sumexp = (float*)alloc(512);
  float* kvm    = (float*)alloc(1572864);  // [B*H][64 d][64 e] f32
  const size_t zbytes = (size_t)((ws + off) - zbase);

  hipMemsetAsync(zbase, 0, zbytes, stream);
  k_prep<<<26880, 256, 0, stream>>>(x, xbf, Wqkv, WqT, Wproj, WpT);
  k_gemm<0><<<dim3(12, 128), 512, 0, stream>>>(xbf, WqT, bqkv, qkv, qsum, ksum, nullptr);
  k_flow1<<<768, 256, 0, stream>>>(qkv, qsum, ksum, si, qsi, kso);
  k_fkv<<<768, 256, 0, stream>>>(qkv, qsi, sumexp, kvm);
  k_xup<<<dim3(32, 96), 256, 0, stream>>>(qkv, kvm, si, kso, sumexp, xbf);
  k_gemm<1><<<dim3(4, 128), 512, 0, stream>>>(xbf, WpT, bproj, nullptr, nullptr, nullptr, out);
}

// Round 19
// 362.157 us; speedup vs baseline: 1.0220x; 1.0071x over previous
//
#include <hip/hip_runtime.h>
#include <stdint.h>

#define EPSF 1e-6f

typedef unsigned short u16;
typedef __attribute__((ext_vector_type(8))) short short8;
typedef __attribute__((ext_vector_type(4))) float f32x4;

__device__ __forceinline__ float us2f(u16 u) {
  union { float f; unsigned int i; } c; c.i = ((unsigned int)u) << 16; return c.f;
}
__device__ __forceinline__ u16 f2bfu(float f) {
  union { float f; unsigned int i; } c; c.f = f;
  unsigned int i = c.i;
  return (u16)((i + 0x7FFFu + ((i >> 16) & 1u)) >> 16);
}
__device__ __forceinline__ float sigm(float x) { return 1.f / (1.f + __expf(-x)); }

typedef __attribute__((address_space(3))) unsigned int lds_u32;
typedef const __attribute__((address_space(1))) unsigned int glb_u32;
__device__ __forceinline__ void gl_lds16(const u16* g, u16* l) {
  __builtin_amdgcn_global_load_lds((glb_u32*)g, (lds_u32*)l, 16, 0, 0);
}

// ---------------- fused prep: x cvt (blocks 0..24575) + W transposes ----------------
__global__ void k_prep(const float* __restrict__ x, u16* __restrict__ xbf,
                       const float* __restrict__ Wqkv, u16* __restrict__ WqT,
                       const float* __restrict__ Wproj, u16* __restrict__ WpT) {
  __shared__ float tile[32][33];
  const int b = blockIdx.x;
  if (b < 24576) {
    const int i = b * 256 + threadIdx.x;
    float4 v = ((const float4*)x)[i];
    ushort4 o;
    o.x = f2bfu(v.x); o.y = f2bfu(v.y); o.z = f2bfu(v.z); o.w = f2bfu(v.w);
    ((ushort4*)xbf)[i] = o;
    return;
  }
  const float* in; u16* out; int R, C, bx, by;
  if (b < 24576 + 1728) {
    const int id = b - 24576; in = Wqkv; out = WqT; R = 768; C = 2304; bx = id % 72; by = id / 72;
  } else {
    const int id = b - 26304; in = Wproj; out = WpT; R = 768; C = 768; bx = id % 24; by = id / 24;
  }
  const int tx = threadIdx.x & 31, ty = threadIdx.x >> 5;
  const int c0 = bx << 5, r0 = by << 5;
  for (int i = ty; i < 32; i += 8) tile[i][tx] = in[(size_t)(r0 + i) * C + c0 + tx];
  __syncthreads();
  for (int i = ty; i < 32; i += 8) out[(size_t)(c0 + i) * R + r0 + tx] = f2bfu(tile[tx][i]);
}

// ---------------- GEMM: 256x192 tile, 8 waves (4x2 grid, 64x96/wave), BK=64, 1 barrier/tile ----------------
// Round-18 schedule (split staging, single setprio region split, 1 barrier/tile) with the wave
// grid re-partitioned 2x4 -> 4x2: frag reads drop 22 -> 20 per tile (perimeter 128+48 -> 64+96),
// the binding LDS-read path. Same LDS layout, same zero-conflict swizzle (bands 16-aligned ->
// read key r16&7 unchanged), same per-acc K-order -> bit-identical output.
template <int MODE>
__global__ __launch_bounds__(512, 1) void k_gemm(
    const u16* __restrict__ A, const u16* __restrict__ BT,
    const float* __restrict__ bias,
    u16* __restrict__ qkvo, float* __restrict__ qsum, float* __restrict__ ksum,
    float* __restrict__ outf)
{
  __shared__ __align__(16) u16 smem[57344];  // 112 KB
  const int tid = threadIdx.x;
  const int lane = tid & 63;
  const int wid = tid >> 6;           // 0..7
  const int wm = wid >> 1, wn = wid & 1;   // 4x2 wave grid: 64 rows x 96 cols per wave
  // bijective XCD swizzle (nwg % 8 == 0 for both grids)
  const int nx = gridDim.x;
  int lid = blockIdx.y * nx + blockIdx.x;
  const int q8 = (nx * gridDim.y) >> 3;
  lid = (lid & 7) * q8 + (lid >> 3);
  const int m0 = (lid / nx) << 8;
  const int n0 = (lid % nx) * 192;

  const int rowL0 = tid >> 3;                      // 0..63
  const int gc = (tid & 7) ^ (rowL0 & 7);
  const u16* gA = A  + (size_t)(m0 + rowL0) * 768 + (gc << 3);
  const u16* gB = BT + (size_t)(n0 + rowL0) * 768 + (gc << 3);

  const int r16 = lane & 15;
  const int sgrp = lane >> 4;
  const int xk = r16 & 7;
  const int coff0 = ((sgrp) ^ xk) << 3;            // kslot 0 chunk offset (elems)
  const int coff1 = ((4 + sgrp) ^ xk) << 3;        // kslot 1
  // A: unit = wm>>1 (128-row halves), row-in-unit = (wm&1)*64 + mi*16 + r16
  int offA[4];
#pragma unroll
  for (int mi = 0; mi < 4; ++mi)
    offA[mi] = ((((wm & 1) << 6) + (mi << 4) + r16) << 6);
  const int paU = (wm >> 1) << 13;                 // A unit base (elems)
  // B: bands ub = wn*96 + nj*16 (16-aligned, never straddle 64-row units)
  int offB[6];
#pragma unroll
  for (int nj = 0; nj < 6; ++nj) {
    const int ub = wn * 96 + (nj << 4);
    offB[nj] = ((ub >> 6) << 12) + (((ub & 63) + r16) << 6);
  }

  f32x4 acc[4][6];
#pragma unroll
  for (int i = 0; i < 4; ++i)
#pragma unroll
    for (int j = 0; j < 6; ++j) acc[i][j] = (f32x4){0.f, 0.f, 0.f, 0.f};

#define STAGEA(tt, y)                                                         \
  do {                                                                        \
    u16* dst = &smem[(((tt) & 1) * 28672) + ((y) << 13) + (tid << 3)];        \
    const u16* s = gA + (size_t)(y) * 98304 + (tt) * 64;                      \
    gl_lds16(s, dst);                                                         \
    gl_lds16(s + 49152, dst + 4096);                                          \
  } while (0)

#define STAGEB(tt, u)                                                         \
  do {                                                                        \
    u16* dst = &smem[(((tt) & 1) * 28672) + 16384 + ((u) << 12) + (tid << 3)];\
    gl_lds16(gB + (size_t)(u) * 49152 + (tt) * 64, dst);                      \
  } while (0)

#define RDA(mi, co) (*(const short8*)(pa + offA[mi] + (co)))
#define RDB(nj, co) (*(const short8*)(pb + offB[nj] + (co)))

// one A frag against all 6 B frags of kslot ks
#define MFMA6(mi, ks, AV)                                                                     \
  do {                                                                                        \
    acc[mi][0] = __builtin_amdgcn_mfma_f32_16x16x32_bf16(AV, bf[0][ks], acc[mi][0], 0, 0, 0); \
    acc[mi][1] = __builtin_amdgcn_mfma_f32_16x16x32_bf16(AV, bf[1][ks], acc[mi][1], 0, 0, 0); \
    acc[mi][2] = __builtin_amdgcn_mfma_f32_16x16x32_bf16(AV, bf[2][ks], acc[mi][2], 0, 0, 0); \
    acc[mi][3] = __builtin_amdgcn_mfma_f32_16x16x32_bf16(AV, bf[3][ks], acc[mi][3], 0, 0, 0); \
    acc[mi][4] = __builtin_amdgcn_mfma_f32_16x16x32_bf16(AV, bf[4][ks], acc[mi][4], 0, 0, 0); \
    acc[mi][5] = __builtin_amdgcn_mfma_f32_16x16x32_bf16(AV, bf[5][ks], acc[mi][5], 0, 0, 0); \
  } while (0)

  STAGEA(0, 0); STAGEA(0, 1); STAGEB(0, 0); STAGEB(0, 1); STAGEB(0, 2);
  asm volatile("s_waitcnt vmcnt(0)" ::: "memory");
  __builtin_amdgcn_s_barrier();

  for (int t = 0; t < 12; ++t) {
    const u16* pa = &smem[(t & 1) * 28672 + paU];
    const u16* pb = &smem[(t & 1) * 28672 + 16384];
    short8 bf[6][2];
#pragma unroll
    for (int nj = 0; nj < 6; ++nj) {
      bf[nj][0] = RDB(nj, coff0);
      bf[nj][1] = RDB(nj, coff1);
    }
    short8 a0 = RDA(0, coff0);
    short8 a1 = RDA(1, coff0);
    if (t < 11) { STAGEA(t + 1, 0); STAGEA(t + 1, 1); }
    __builtin_amdgcn_s_setprio(1);
    // kslot 0 first for every acc element, then kslot 1 (same order as prior rounds)
    MFMA6(0, 0, a0);
    MFMA6(1, 0, a1);
    a0 = RDA(2, coff0);
    a1 = RDA(3, coff0);
    __builtin_amdgcn_s_setprio(0);
    if (t < 11) { STAGEB(t + 1, 0); STAGEB(t + 1, 1); STAGEB(t + 1, 2); }
    __builtin_amdgcn_s_setprio(1);
    MFMA6(2, 0, a0);
    MFMA6(3, 0, a1);
    a0 = RDA(0, coff1);
    a1 = RDA(1, coff1);
    MFMA6(0, 1, a0);
    MFMA6(1, 1, a1);
    a0 = RDA(2, coff1);
    a1 = RDA(3, coff1);
    MFMA6(2, 1, a0);
    MFMA6(3, 1, a1);
    __builtin_amdgcn_s_setprio(0);
    asm volatile("s_waitcnt vmcnt(0)" ::: "memory");  // next tile landed; clobber pins LDS-read hoisting
    __builtin_amdgcn_s_barrier();                     // all waves' tile-t reads consumed before slot reuse
  }
#undef MFMA6
#undef RDA
#undef RDB
#undef STAGEA
#undef STAGEB

  if (MODE == 0) {
    // tile is entirely q (n0<768), k (768<=n0<1536) or v (n0>=1536): 768 = 4*192
    const bool sg = (n0 < 1536);
    const int colc = n0 + wn * 96;
    float jsum[6] = {0.f, 0.f, 0.f, 0.f, 0.f, 0.f};
#pragma unroll
    for (int mi = 0; mi < 4; ++mi) {
      const int rowb = m0 + (wm << 6) + (mi << 4) + ((lane >> 4) << 2);
#pragma unroll
      for (int nj = 0; nj < 6; ++nj) {
        const int col = colc + (nj << 4) + r16;
        const float bcol = bias[col];
        if (sg) {
#pragma unroll
          for (int rg = 0; rg < 4; ++rg) {
            const float val = sigm(acc[mi][nj][rg] + bcol);
            jsum[nj] += val;
            qkvo[(size_t)(rowb + rg) * 2304 + col] = f2bfu(val);
          }
        } else {
#pragma unroll
          for (int rg = 0; rg < 4; ++rg)
            qkvo[(size_t)(rowb + rg) * 2304 + col] = f2bfu(acc[mi][nj][rg] + bcol);
        }
      }
    }
    if (sg) {
#pragma unroll
      for (int nj = 0; nj < 6; ++nj) {
        jsum[nj] += __shfl_xor(jsum[nj], 16, 64);
        jsum[nj] += __shfl_xor(jsum[nj], 32, 64);
      }
      if (lane < 16) {
        const int b768 = (m0 >> 12) * 768;
        float* sdst = (n0 >= 768) ? ksum : qsum;
        const int cb = colc - ((n0 >= 768) ? 768 : 0);
#pragma unroll
        for (int nj = 0; nj < 6; ++nj)
          atomicAdd(&sdst[b768 + cb + (nj << 4) + r16], jsum[nj]);
      }
    }
  } else {
#pragma unroll
    for (int mi = 0; mi < 4; ++mi) {
      const int rowb = m0 + (wm << 6) + (mi << 4) + ((lane >> 4) << 2);
#pragma unroll
      for (int nj = 0; nj < 6; ++nj) {
        const int col = n0 + wn * 96 + (nj << 4) + r16;
        const float bcol = bias[col];
#pragma unroll
        for (int rg = 0; rg < 4; ++rg)
          outf[(size_t)(rowb + rg) * 768 + col] = sigm(2.f * (acc[mi][nj][rg] + bcol));
      }
    }
  }
}

// ---------------- si/so + qsi/kso: 8-lane groups, 16B loads, 4-row ILP ----------------
__global__ __launch_bounds__(256) void k_flow1(
    const u16* __restrict__ qkv,
    const float* __restrict__ qsum, const float* __restrict__ ksum,
    float* __restrict__ si_out, float* __restrict__ qsi, float* __restrict__ kso)
{
  const int bh = blockIdx.x >> 3, sp = blockIdx.x & 7;
  const int tid = threadIdx.x;
  const int grp = tid >> 3;
  const int d0 = (tid & 7) << 3;
  const u16* base = qkv + (size_t)(bh / 12) * 4096 * 2304 + (bh % 12) * 64;

  float ke[8], qe[8];
#pragma unroll
  for (int u = 0; u < 8; ++u) {
    ke[u] = ksum[(bh << 6) + d0 + u] + EPSF;
    qe[u] = qsum[(bh << 6) + d0 + u] + EPSF;
  }
  float Sk = 0.f, Sq = 0.f;
#pragma unroll
  for (int u = 0; u < 8; ++u) { Sk += ke[u]; Sq += qe[u]; }
#pragma unroll
  for (int m = 1; m < 8; m <<= 1) { Sk += __shfl_xor(Sk, m, 64); Sq += __shfl_xor(Sq, m, 64); }
  const float cK = EPSF * Sk + EPSF;
  const float cQ = EPSF * Sq + EPSF;

  float aq[8], ak[8];
#pragma unroll
  for (int u = 0; u < 8; ++u) { aq[u] = 0.f; ak[u] = 0.f; }

  const int nbase = sp << 9;
#pragma unroll 4
  for (int it = 0; it < 16; ++it) {
    const int n = nbase + (it << 5) + grp;
    const u16* rp = base + (size_t)n * 2304 + d0;
    short8 q8 = *(const short8*)(rp);
    short8 k8 = *(const short8*)(rp + 768);
    float dq = 0.f, dk = 0.f;
#pragma unroll
    for (int u = 0; u < 8; ++u) {
      dq += us2f((u16)q8[u]) * ke[u];
      dk += us2f((u16)k8[u]) * qe[u];
    }
#pragma unroll
    for (int m = 1; m < 8; m <<= 1) { dq += __shfl_xor(dq, m, 64); dk += __shfl_xor(dk, m, 64); }
    const float si = 1.f / (dq + cK);
    const float so = 1.f / (dk + cQ);
    if ((tid & 7) == 0) si_out[(bh << 12) + n] = si;
#pragma unroll
    for (int u = 0; u < 8; ++u) {
      aq[u] += us2f((u16)q8[u]) * si;
      ak[u] += us2f((u16)k8[u]) * so;
    }
  }
  __shared__ float redq[32][68];
  __shared__ float redk[32][68];
#pragma unroll
  for (int u = 0; u < 8; ++u) { redq[grp][d0 + u] = aq[u]; redk[grp][d0 + u] = ak[u]; }
  __syncthreads();
  if (tid < 128) {
    const int which = tid >> 6, d = tid & 63;
    float s = 0.f;
    if (which == 0) {
#pragma unroll
      for (int g = 0; g < 32; ++g) s += redq[g][d];
      atomicAdd(&qsi[(bh << 6) + d], s);
    } else {
#pragma unroll
      for (int g = 0; g < 32; ++g) s += redk[g][d];
      atomicAdd(&kso[(bh << 6) + d], s);
    }
  }
}

// ---------------- fused kv (MFMA): e/sumexp inline, kvm[d][e] accumulate ----------------
__global__ __launch_bounds__(256) void k_fkv(
    const u16* __restrict__ qkv,
    const float* __restrict__ qsi,
    float* __restrict__ sumexp, float* __restrict__ kvm)
{
  __shared__ __align__(16) u16 smem[2 * 64 * 136];  // 34816 B; reused as f32 reduce buf
  u16* kT = smem;
  u16* vT = smem + 64 * 136;
  const int tid = threadIdx.x;
  const int bh = blockIdx.x >> 3, sp = blockIdx.x & 7;
  const int lane = tid & 63, wid = tid >> 6;
  const int r16 = lane & 15, g = lane >> 4;
  const u16* base = qkv + (size_t)(bh / 12) * 4096 * 2304 + (bh % 12) * 64;

  const int d0 = (tid & 7) << 3;
  float qie[8];
#pragma unroll
  for (int u = 0; u < 8; ++u) qie[u] = qsi[(bh << 6) + d0 + u] + EPSF;
  float Sq = qsi[(bh << 6) + lane] + EPSF;
#pragma unroll
  for (int m = 1; m < 64; m <<= 1) Sq += __shfl_xor(Sq, m, 64);
  const float cR = EPSF * Sq + EPSF;

  f32x4 acc[4][4];
#pragma unroll
  for (int i = 0; i < 4; ++i)
#pragma unroll
    for (int j = 0; j < 4; ++j) acc[i][j] = (f32x4){0.f, 0.f, 0.f, 0.f};

  const int nf = (wid << 5) + (g << 3);
  float esum = 0.f;

  for (int st = 0; st < 4; ++st) {
    const int nst = (sp << 9) + (st << 7);
    // issue all 4 row-pair loads first (ILP), then process
    short8 k8v[4], v8v[4];
#pragma unroll
    for (int i = 0; i < 4; ++i) {
      const int c = tid + (i << 8);
      const int nl = c >> 3;
      const u16* rp = base + (size_t)(nst + nl) * 2304 + d0;
      k8v[i] = *(const short8*)(rp + 768);
      v8v[i] = *(const short8*)(rp + 1536);
    }
#pragma unroll
    for (int i = 0; i < 4; ++i) {
      const int c = tid + (i << 8);
      const int nl = c >> 3;
      short8 k8 = k8v[i], v8 = v8v[i];
      float pcr = 0.f;
#pragma unroll
      for (int u = 0; u < 8; ++u) pcr += us2f((u16)k8[u]) * qie[u];
#pragma unroll
      for (int m = 1; m < 8; m <<= 1) pcr += __shfl_xor(pcr, m, 64);
      float cr = pcr + cR;
      cr = fminf(1.f, fmaxf(-1.f, cr));
      const float ev = __expf(cr);
      const int col = nl ^ (d0 & 56);
#pragma unroll
      for (int u = 0; u < 8; ++u) {
        kT[(d0 + u) * 136 + col] = f2bfu(us2f((u16)k8[u]) * ev);
        vT[(d0 + u) * 136 + col] = (u16)(unsigned short)v8[u];
      }
      if ((tid & 7) == 0) esum += ev;
    }
    __syncthreads();

    short8 af[4], bf[4];
#pragma unroll
    for (int mi = 0; mi < 4; ++mi) {
      const int row = (mi << 4) + r16;
      af[mi] = *(const short8*)&kT[row * 136 + (nf ^ (row & 56))];
    }
#pragma unroll
    for (int nj = 0; nj < 4; ++nj) {
      const int row = (nj << 4) + r16;
      bf[nj] = *(const short8*)&vT[row * 136 + (nf ^ (row & 56))];
    }
#pragma unroll
    for (int mi = 0; mi < 4; ++mi)
#pragma unroll
      for (int nj = 0; nj < 4; ++nj)
        acc[mi][nj] = __builtin_amdgcn_mfma_f32_16x16x32_bf16(af[mi], bf[nj], acc[mi][nj], 0, 0, 0);
    __syncthreads();
  }

  // cross-wave reduce (two 32-d halves through LDS) + coalesced atomics
  float* red = (float*)smem;
  float* kvb = kvm + ((size_t)bh << 12);
#pragma unroll
  for (int half = 0; half < 2; ++half) {
#pragma unroll
    for (int m2 = 0; m2 < 2; ++m2) {
      const int mi = (half << 1) + m2;
#pragma unroll
      for (int nj = 0; nj < 4; ++nj)
#pragma unroll
        for (int rg = 0; rg < 4; ++rg)
          red[(wid << 11) + (((m2 << 4) + (g << 2) + rg) << 6) + (nj << 4) + r16] = acc[mi][nj][rg];
    }
    __syncthreads();
    const int base2 = tid << 3;
#pragma unroll
    for (int u2 = 0; u2 < 2; ++u2) {
      const int o = base2 + (u2 << 2);
      float4 s0 = *(const float4*)&red[o];
      float4 s1 = *(const float4*)&red[2048 + o];
      float4 s2 = *(const float4*)&red[4096 + o];
      float4 s3 = *(const float4*)&red[6144 + o];
      s0.x += s1.x + s2.x + s3.x;
      s0.y += s1.y + s2.y + s3.y;
      s0.z += s1.z + s2.z + s3.z;
      s0.w += s1.w + s2.w + s3.w;
      const int gi = (half << 11) + o;
      atomicAdd(&kvb[gi + 0], s0.x);
      atomicAdd(&kvb[gi + 1], s0.y);
      atomicAdd(&kvb[gi + 2], s0.z);
      atomicAdd(&kvb[gi + 3], s0.w);
    }
    __syncthreads();
  }

  esum += __shfl_xor(esum, 8, 64);
  esum += __shfl_xor(esum, 16, 64);
  esum += __shfl_xor(esum, 32, 64);
  if (lane == 0) atomicAdd(&sumexp[bh], esum);
}

// ---------------- x_update = (q @ kv) * m[n] * scale; m computed inline from q,kso,si ----------------
__global__ __launch_bounds__(256) void k_xup(
    const u16* __restrict__ qkv, const float* __restrict__ kvm,
    const float* __restrict__ si_arr, const float* __restrict__ kso,
    const float* __restrict__ sumexp,
    u16* __restrict__ attn)
{
  const int bh = blockIdx.y;
  const int n0 = blockIdx.x << 7;
  const int b = bh / 12, h = bh % 12;
  __shared__ __align__(16) u16 qs[128 * 72];
  __shared__ __align__(16) u16 kvs[64 * 72];
  __shared__ float m_lds[128];
  const int tid = threadIdx.x, lane = tid & 63, wid = tid >> 6;
  const int d0c = (tid & 7) << 3;

  float soe[8];
#pragma unroll
  for (int u = 0; u < 8; ++u) soe[u] = kso[(bh << 6) + d0c + u] + EPSF;
  float Ss = 0.f;
#pragma unroll
  for (int u = 0; u < 8; ++u) Ss += soe[u];
#pragma unroll
  for (int m = 1; m < 8; m <<= 1) Ss += __shfl_xor(Ss, m, 64);
  const float cS = EPSF * Ss + EPSF;

  const u16* qg = qkv + (size_t)b * 4096 * 2304 + (size_t)n0 * 2304 + h * 64;
#pragma unroll
  for (int i = 0; i < 4; ++i) {
    const int c = tid + (i << 8);
    const int nl = c >> 3, d0 = (c & 7) << 3;
    short8 q8 = *(const short8*)(qg + (size_t)nl * 2304 + d0);
    *(short8*)&qs[nl * 72 + d0] = q8;
    float pcs = 0.f;
#pragma unroll
    for (int u = 0; u < 8; ++u) pcs += us2f((u16)q8[u]) * soe[u];
#pragma unroll
    for (int m = 1; m < 8; m <<= 1) pcs += __shfl_xor(pcs, m, 64);
    if ((tid & 7) == 0)
      m_lds[nl] = si_arr[((size_t)bh << 12) + n0 + nl] * sigm(pcs + cS);
  }
  const float* kvg = kvm + ((size_t)bh << 12);
#pragma unroll
  for (int i = 0; i < 4; ++i) {
    const int idx = (tid << 2) + (i << 10);
    const int d = idx >> 6, e0 = idx & 63;
    float4 vv = *(const float4*)(kvg + idx);
    kvs[(e0 + 0) * 72 + d] = f2bfu(vv.x);
    kvs[(e0 + 1) * 72 + d] = f2bfu(vv.y);
    kvs[(e0 + 2) * 72 + d] = f2bfu(vv.z);
    kvs[(e0 + 3) * 72 + d] = f2bfu(vv.w);
  }
  __syncthreads();
  const float scale = 4096.f / sumexp[bh];
  const int r16 = lane & 15, kg8 = (lane >> 4) << 3;
  f32x4 acc[2][4];
#pragma unroll
  for (int i = 0; i < 2; ++i)
#pragma unroll
    for (int j = 0; j < 4; ++j) acc[i][j] = (f32x4){0.f, 0.f, 0.f, 0.f};
#pragma unroll
  for (int kk = 0; kk < 2; ++kk) {
    short8 af[2], bfv[4];
#pragma unroll
    for (int mi = 0; mi < 2; ++mi)
      af[mi] = *(const short8*)&qs[((wid << 5) + (mi << 4) + r16) * 72 + (kk << 5) + kg8];
#pragma unroll
    for (int nj = 0; nj < 4; ++nj)
      bfv[nj] = *(const short8*)&kvs[((nj << 4) + r16) * 72 + (kk << 5) + kg8];
#pragma unroll
    for (int mi = 0; mi < 2; ++mi)
#pragma unroll
      for (int nj = 0; nj < 4; ++nj)
        acc[mi][nj] = __builtin_amdgcn_mfma_f32_16x16x32_bf16(af[mi], bfv[nj], acc[mi][nj], 0, 0, 0);
  }
#pragma unroll
  for (int mi = 0; mi < 2; ++mi) {
#pragma unroll
    for (int rg = 0; rg < 4; ++rg) {
      const int nloc = (wid << 5) + (mi << 4) + ((lane >> 4) << 2) + rg;
      const int n = n0 + nloc;
      const float mult = m_lds[nloc] * scale;
#pragma unroll
      for (int nj = 0; nj < 4; ++nj) {
        const int e = (nj << 4) + r16;
        attn[((size_t)(b * 4096 + n)) * 768 + (h << 6) + e] = f2bfu(acc[mi][nj][rg] * mult);
      }
    }
  }
}

extern "C" void kernel_launch(void* const* d_in, const int* in_sizes, int n_in,
                              void* d_out, int out_size, void* d_ws, size_t ws_size,
                              hipStream_t stream)
{
  (void)in_sizes; (void)n_in; (void)out_size; (void)ws_size;
  const float* x     = (const float*)d_in[0];
  const float* Wqkv  = (const float*)d_in[1];
  const float* bqkv  = (const float*)d_in[2];
  const float* Wproj = (const float*)d_in[3];
  const float* bproj = (const float*)d_in[4];
  float* out = (float*)d_out;

  char* ws = (char*)d_ws;
  size_t off = 0;
  auto alloc = [&](size_t bytes) -> char* {
    char* p = ws + off;
    off += (bytes + 255) & ~(size_t)255;
    return p;
  };
  u16* qkv  = (u16*)alloc(150994944);      // [32768][2304] bf16 flat (q|k|v)
  u16* xbf  = (u16*)alloc(50331648);       // x bf16; reused as attn output
  u16* WqT  = (u16*)alloc(3538944);        // [2304][768] bf16
  u16* WpT  = (u16*)alloc(1179648);        // [768][768] bf16
  float* si = (float*)alloc(1572864);      // [B*H][N]
  char* zbase = ws + off;
  float* qsum   = (float*)alloc(24576);
  float* ksum   = (float*)alloc(24576);
  float* qsi    = (float*)alloc(24576);
  float* kso    = (float*)alloc(24576);
  float* sumexp = (float*)alloc(512);
  float* kvm    = (float*)alloc(1572864);  // [B*H][64 d][64 e] f32
  const size_t zbytes = (size_t)((ws + off) - zbase);

  hipMemsetAsync(zbase, 0, zbytes, stream);
  k_prep<<<26880, 256, 0, stream>>>(x, xbf, Wqkv, WqT, Wproj, WpT);
  k_gemm<0><<<dim3(12, 128), 512, 0, stream>>>(xbf, WqT, bqkv, qkv, qsum, ksum, nullptr);
  k_flow1<<<768, 256, 0, stream>>>(qkv, qsum, ksum, si, qsi, kso);
  k_fkv<<<768, 256, 0, stream>>>(qkv, qsi, sumexp, kvm);
  k_xup<<<dim3(32, 96), 256, 0, stream>>>(qkv, kvm, si, kso, sumexp, xbf);
  k_gemm<1><<<dim3(4, 128), 512, 0, stream>>>(xbf, WpT, bproj, nullptr, nullptr, nullptr, out);
}